// Round 7
// baseline (8572.469 us; speedup 1.0000x reference)
//
#include <hip/hip_runtime.h>
#include <math.h>
#include <stdint.h>

#define BATCH 4
#define CH 128
#define NPIX 4096
#define DQKD 16
#define QB 64
#define KVB 64
#define NTHREADS 256

typedef _Float16 f16;
typedef _Float16 f16x8 __attribute__((ext_vector_type(8)));
typedef float f32x16 __attribute__((ext_vector_type(16)));
typedef uint32_t u32;

__device__ inline f32x16 zero16() {
    f32x16 z;
    #pragma unroll
    for (int i = 0; i < 16; ++i) z[i] = 0.0f;
    return z;
}

__device__ inline u32 pk2(float a, float b) {
    auto h = __builtin_amdgcn_cvt_pkrtz(a, b);   // 2 x f16 packed, RTZ
    return __builtin_bit_cast(u32, h);
}

// ---------------------------------------------------------------------------
// DIAGNOSTIC projection (exonerated in round 5): one thread = one (row, n).
// Outputs: Qg[b][n][16] f16, Kg[b][n][16] f16, Vg[b][c][n] f16.
// ---------------------------------------------------------------------------
__global__ __launch_bounds__(NTHREADS) void proj_simple(
    const float* __restrict__ x,
    const float* __restrict__ Wq, const float* __restrict__ bq,
    const float* __restrict__ Wk, const float* __restrict__ bk,
    const float* __restrict__ Wv, const float* __restrict__ bv,
    f16* __restrict__ Qg, f16* __restrict__ Kg, f16* __restrict__ Vg)
{
    const int bid = blockIdx.x;                 // = ((b*160)+row)*16 + nc
    const int nc  = bid & 15;
    const int row = (bid >> 4) % 160;
    const int b   = bid / 2560;
    const int n   = nc * 256 + threadIdx.x;

    const float* wrow;
    float acc;
    if (row < 16)      { wrow = Wq + row * CH;        acc = bq[row]; }
    else if (row < 32) { wrow = Wk + (row - 16) * CH; acc = bk[row - 16]; }
    else               { wrow = Wv + (row - 32) * CH; acc = bv[row - 32]; }

    const float* xb = x + (size_t)b * CH * NPIX + n;  // x[b][c][n], c-stride NPIX
    #pragma unroll 4
    for (int c = 0; c < CH; ++c) acc += wrow[c] * xb[(size_t)c * NPIX];

    const f16 h = (f16)acc;
    if (row < 16)      Qg[(((size_t)(b * NPIX + n)) << 4) + row] = h;
    else if (row < 32) Kg[(((size_t)(b * NPIX + n)) << 4) + (row - 16)] = h;
    else               Vg[((size_t)(b * CH) + (row - 32)) * NPIX + n] = h;
}

// ---------------------------------------------------------------------------
// DIAGNOSTIC attention: Half A (QK^T MFMA + softmax + P->LDS) byte-identical
// to round 4/5. Half B replaced by correct-by-construction fp32 VALU PV:
// P read scalar from the same Ps buffer/swizzle; V read directly from global.
// ---------------------------------------------------------------------------
__global__ __launch_bounds__(NTHREADS) void attn_diag(
    const f16* __restrict__ Qg, const f16* __restrict__ Kg, const f16* __restrict__ Vg,
    const float* __restrict__ x, const float* __restrict__ gamma_p,
    float* __restrict__ out)
{
    __shared__ __align__(16) f16 Ps[64 * 64];      // 8 KB swizzled [q][key]
    __shared__ float scs[64];
    __shared__ float ls[64];

    int bid = blockIdx.x;
    bid = (bid & 7) * 32 + (bid >> 3);             // XCD swizzle (bijective, 256=8*32)
    const int b  = bid >> 6;
    const int n0 = (bid & 63) * 64;
    const int tid  = threadIdx.x;
    const int lane = tid & 63;
    const int w    = tid >> 6;
    const int qh = w & 1, chh = w >> 1;
    const int lo = lane & 31, hi = lane >> 5;
    const float g = gamma_p[0];

    const f16* Vb = Vg + (size_t)b * CH * NPIX;
    const f16* Kb = Kg + ((size_t)(b * NPIX) << 4);

    const f16x8 qf = *(const f16x8*)(Qg + ((size_t)(b * NPIX + n0 + qh * 32 + lo) << 4) + hi * 8);

    const int qrow = qh * 32 + lo;                 // this lane's softmax row
    char* pbase = ((char*)Ps) + qrow * 128;
    const int sw = (lo & 7) << 4;

    // VALU-PV ownership: thread -> (query vq, 32 channels starting at cb)
    const int vq = tid >> 2;                       // 0..63
    const int cb = (tid & 3) * 32;                 // 0,32,64,96
    const char* prow = ((const char*)Ps) + vq * 128;
    const int swq = (vq & 7) << 4;

    float acc[32];
    #pragma unroll
    for (int j = 0; j < 32; ++j) acc[j] = 0.0f;

    float m_i = -1e30f, l_i = 0.0f;

    for (int t = 0; t < NPIX / KVB; ++t) {
        __syncthreads();   // (A) prev-tile PV reads of Ps/scs are done

        // ---- Half A: QK^T MFMA (identical to round 4/5) ----
        const f16* kt = Kb + ((size_t)(t * KVB) << 4);
        const f16x8 kf0 = *(const f16x8*)(kt + (lo << 4) + hi * 8);
        const f16x8 kf1 = *(const f16x8*)(kt + ((32 + lo) << 4) + hi * 8);

        f32x16 e0 = __builtin_amdgcn_mfma_f32_32x32x16_f16(kf0, qf, zero16(), 0, 0, 0);
        f32x16 e1 = __builtin_amdgcn_mfma_f32_32x32x16_f16(kf1, qf, zero16(), 0, 0, 0);

        float pmax = e0[0];
        #pragma unroll
        for (int j = 1; j < 16; ++j) pmax = fmaxf(pmax, e0[j]);
        #pragma unroll
        for (int j = 0; j < 16; ++j) pmax = fmaxf(pmax, e1[j]);
        pmax = fmaxf(pmax, __shfl_xor(pmax, 32));
        const float m_new = fmaxf(m_i, pmax);
        const float sc = __expf(m_i - m_new);
        float psum = 0.0f;
        #pragma unroll
        for (int j = 0; j < 16; ++j) { e0[j] = __expf(e0[j] - m_new); psum += e0[j]; }
        #pragma unroll
        for (int j = 0; j < 16; ++j) { e1[j] = __expf(e1[j] - m_new); psum += e1[j]; }
        psum += __shfl_xor(psum, 32);
        l_i = l_i * sc + psum;
        m_i = m_new;

        if (chh == 0 && hi == 0) scs[qrow] = sc;

        // ---- P -> LDS (identical mapping to round 4/5) ----
        #pragma unroll
        for (int j = 0; j < 16; j += 2) {
            const int k0 = (j & 3) + 8 * (j >> 2) + 4 * hi;
            *(u32*)(pbase + ((2 * k0) ^ sw))      = pk2(e0[j], e0[j + 1]);
            *(u32*)(pbase + ((2 * k0 + 64) ^ sw)) = pk2(e1[j], e1[j + 1]);
        }

        __syncthreads();   // (B) Ps + scs visible

        // ---- Half B (diagnostic): fp32 VALU PV, V from global ----
        const float scq = scs[vq];
        #pragma unroll
        for (int j = 0; j < 32; ++j) acc[j] *= scq;

        const f16* vt = Vb + (size_t)(t * KVB);    // + k + c*NPIX
        for (int k = 0; k < KVB; ++k) {
            const float p = (float)*(const f16*)(prow + ((2 * k) ^ swq));
            const f16* vcol = vt + k;
            #pragma unroll 8
            for (int j = 0; j < 32; ++j)
                acc[j] += p * (float)vcol[(size_t)(cb + j) * NPIX];
        }
    }

    if (chh == 0 && hi == 0) ls[qrow] = l_i;
    __syncthreads();

    const float linv = 1.0f / ls[vq];
    const size_t base = ((size_t)(b * NPIX + n0 + vq)) << 7;  // *128
    #pragma unroll 8
    for (int j = 0; j < 32; ++j)
        out[base + cb + j] = g * (acc[j] * linv) + x[base + cb + j];
}

extern "C" void kernel_launch(void* const* d_in, const int* in_sizes, int n_in,
                              void* d_out, int out_size, void* d_ws, size_t ws_size,
                              hipStream_t stream) {
    const float* x     = (const float*)d_in[0];
    const float* Wq    = (const float*)d_in[1];
    const float* bq    = (const float*)d_in[2];
    const float* Wk    = (const float*)d_in[3];
    const float* bk    = (const float*)d_in[4];
    const float* Wv    = (const float*)d_in[5];
    const float* bv    = (const float*)d_in[6];
    const float* gamma = (const float*)d_in[7];
    float* out = (float*)d_out;

    f16* Qg = (f16*)d_ws;                                   // 512 KB
    f16* Kg = Qg + (size_t)BATCH * NPIX * DQKD;             // 512 KB
    f16* Vg = Kg + (size_t)BATCH * NPIX * DQKD;             // 4 MB

    proj_simple<<<dim3(BATCH * 160 * 16), NTHREADS, 0, stream>>>(
        x, Wq, bq, Wk, bk, Wv, bv, Qg, Kg, Vg);
    attn_diag<<<dim3(BATCH * (NPIX / QB)), NTHREADS, 0, stream>>>(
        Qg, Kg, Vg, x, gamma, out);
}

// Round 8
// 287.498 us; speedup vs baseline: 29.8174x; 29.8174x over previous
//
#include <hip/hip_runtime.h>
#include <math.h>
#include <stdint.h>

#define BATCH 4
#define CH 128
#define NPIX 4096
#define DQKD 16
#define QB 64
#define KVB 64
#define NTHREADS 256

typedef _Float16 f16;
typedef _Float16 f16x8 __attribute__((ext_vector_type(8)));
typedef float f32x16 __attribute__((ext_vector_type(16)));
typedef uint32_t u32;

__device__ inline f32x16 zero16() {
    f32x16 z;
    #pragma unroll
    for (int i = 0; i < 16; ++i) z[i] = 0.0f;
    return z;
}

__device__ inline u32 pk2(float a, float b) {
    auto h = __builtin_amdgcn_cvt_pkrtz(a, b);   // 2 x f16 packed, RTZ
    return __builtin_bit_cast(u32, h);
}

// ---------------------------------------------------------------------------
// Projection GEMM: [160 rows = q16|k16|v128][128 c] x [128 c][N] via MFMA.
// Outputs: Qg[b][n][16] f16, Kg[b][n][16] f16, Vg[b][c][n] f16.
// (Exonerated by round-5 bisection: identical failure signature as scalar.)
// ---------------------------------------------------------------------------
__global__ __launch_bounds__(NTHREADS) void proj_mfma(
    const float* __restrict__ x,
    const float* __restrict__ Wq, const float* __restrict__ bq,
    const float* __restrict__ Wk, const float* __restrict__ bk,
    const float* __restrict__ Wv, const float* __restrict__ bv,
    f16* __restrict__ Qg, f16* __restrict__ Kg, f16* __restrict__ Vg)
{
    __shared__ __align__(16) f16 xs[64 * 128];  // swizzled [n][c], 16 KB
    const int bid = blockIdx.x;
    const int b  = bid >> 6;
    const int n0 = (bid & 63) * 64;
    const int tid = threadIdx.x;

    // stage x[b][c][n0..n0+63] -> xs[n][c] (f16, 16B-chunk XOR swizzle on n&7)
    {
        const int nn = tid & 63;
        const int ch = (tid >> 6) * 32;
        const float* xp = x + ((size_t)b * CH + ch) * NPIX + n0 + nn;
        float v[32];
        #pragma unroll
        for (int j = 0; j < 32; ++j) v[j] = xp[(size_t)j * NPIX];
        char* xb = (char*)xs;
        #pragma unroll
        for (int qq = 0; qq < 4; ++qq) {
            f16x8 h;
            #pragma unroll
            for (int i = 0; i < 8; ++i) h[i] = (f16)v[qq * 8 + i];
            const int off = nn * 256 + ((ch * 2 + qq * 16) ^ ((nn & 7) << 4));
            *(f16x8*)(xb + off) = h;
        }
    }
    __syncthreads();

    const int lane = tid & 63;
    const int w    = tid >> 6;
    const int lo = lane & 31, hi = lane >> 5;

    for (int idx = w; idx < 10; idx += 4) {
        const int rt = idx >> 1, ns = idx & 1;
        const int grow = rt * 32 + lo;          // global output row 0..159
        const float* wrow;
        if (grow < 16)      wrow = Wq + grow * CH;
        else if (grow < 32) wrow = Wk + (grow - 16) * CH;
        else                wrow = Wv + (grow - 32) * CH;

        f32x16 acc = zero16();
        const int nrow = ns * 32 + lo;          // local n for B frag
        #pragma unroll
        for (int ks = 0; ks < 8; ++ks) {
            const float4 a0 = *(const float4*)(wrow + ks * 16 + hi * 8);
            const float4 a1 = *(const float4*)(wrow + ks * 16 + hi * 8 + 4);
            f16x8 ah;
            ah[0] = (f16)a0.x; ah[1] = (f16)a0.y; ah[2] = (f16)a0.z; ah[3] = (f16)a0.w;
            ah[4] = (f16)a1.x; ah[5] = (f16)a1.y; ah[6] = (f16)a1.z; ah[7] = (f16)a1.w;
            const int off = nrow * 256 + ((ks * 32 + hi * 16) ^ ((nrow & 7) << 4));
            const f16x8 bh = *(const f16x8*)((const char*)xs + off);
            acc = __builtin_amdgcn_mfma_f32_32x32x16_f16(ah, bh, acc, 0, 0, 0);
        }

        const int n = n0 + ns * 32 + lo;        // D col = lane&31
        #pragma unroll
        for (int r = 0; r < 16; ++r) {
            const int rloc = (r & 3) + 8 * (r >> 2) + 4 * hi;
            const int row  = rt * 32 + rloc;
            float bias;
            if (row < 16)      bias = bq[row];
            else if (row < 32) bias = bk[row - 16];
            else               bias = bv[row - 32];
            const float val = acc[r] + bias;
            const f16 hv = (f16)val;
            if (row < 16)      Qg[(((size_t)(b * NPIX + n)) << 4) + row] = hv;
            else if (row < 32) Kg[(((size_t)(b * NPIX + n)) << 4) + (row - 16)] = hv;
            else               Vg[((size_t)(b * CH) + (row - 32)) * NPIX + n] = hv;
        }
    }
}

// ---------------------------------------------------------------------------
// Flash attention (MFMA) + residual. Block: 64 q x all keys; 4 waves =
// 2 q-halves x 2 c-halves. Swapped QK^T -> lane-local softmax row (E-layout).
// FIX vs round 4: online-softmax rescale sc is per-ROW; PV accumulator regs
// are D-layout rows (r&3)+8(r>>2)+4hi, NOT the lane's E-row. Broadcast sc
// via scs[] LDS and rescale per register row (round-7-verified structure).
// ---------------------------------------------------------------------------
__global__ __launch_bounds__(NTHREADS) void attn_mfma(
    const f16* __restrict__ Qg, const f16* __restrict__ Kg, const f16* __restrict__ Vg,
    const float* __restrict__ x, const float* __restrict__ gamma_p,
    float* __restrict__ out)
{
    __shared__ __align__(16) f16 Vs[2][128 * 64];  // 2 x 16 KB swizzled [c][m]
    __shared__ __align__(16) f16 Ps[64 * 64];      // 8 KB swizzled [q][key]
    __shared__ float scs[64];
    __shared__ float ls[64];

    int bid = blockIdx.x;
    bid = (bid & 7) * 32 + (bid >> 3);             // XCD swizzle (bijective, 256=8*32)
    const int b  = bid >> 6;
    const int n0 = (bid & 63) * 64;
    const int tid  = threadIdx.x;
    const int lane = tid & 63;
    const int w    = tid >> 6;
    const int qh = w & 1, chh = w >> 1;
    const int lo = lane & 31, hi = lane >> 5;
    const float g = gamma_p[0];

    const f16* Vb = Vg + (size_t)b * CH * NPIX;
    const f16* Kb = Kg + ((size_t)(b * NPIX) << 4);

    const f16x8 qf = *(const f16x8*)(Qg + ((size_t)(b * NPIX + n0 + qh * 32 + lo) << 4) + hi * 8);

    const int qrow = qh * 32 + lo;                 // this lane's softmax row
    char* pbase = ((char*)Ps) + qrow * 128;
    const int sw = (lo & 7) << 4;

    uint4 sreg[4];
    auto load_tile = [&](int t) {
        const f16* vt = Vb + t * KVB;
        #pragma unroll
        for (int ps = 0; ps < 4; ++ps) {
            const int idx = ps * 256 + tid;
            const int c = idx >> 3, ck = idx & 7;
            sreg[ps] = *(const uint4*)(vt + (size_t)c * NPIX + ck * 8);
        }
    };
    auto write_tile = [&](int p) {
        char* base = (char*)(&Vs[p][0]);
        #pragma unroll
        for (int ps = 0; ps < 4; ++ps) {
            const int idx = ps * 256 + tid;
            const int c = idx >> 3, ck = idx & 7;
            const int off = c * 128 + ((ck * 16) ^ ((c & 7) << 4));
            *(uint4*)(base + off) = sreg[ps];
        }
    };

    f32x16 acc0 = zero16(), acc1 = zero16();
    float m_i = -1e30f, l_i = 0.0f;

    load_tile(0);
    for (int t = 0; t < NPIX / KVB; ++t) {
        const int bufp = t & 1;
        write_tile(bufp);
        __syncthreads();   // (1) Vs[bufp] ready; prev iter's Ps/scs reads done
        if (t < NPIX / KVB - 1) load_tile(t + 1);

        // ---- QK^T (hardware-verified in round 7) ----
        const f16* kt = Kb + ((size_t)(t * KVB) << 4);
        const f16x8 kf0 = *(const f16x8*)(kt + (lo << 4) + hi * 8);
        const f16x8 kf1 = *(const f16x8*)(kt + ((32 + lo) << 4) + hi * 8);

        f32x16 e0 = __builtin_amdgcn_mfma_f32_32x32x16_f16(kf0, qf, zero16(), 0, 0, 0);
        f32x16 e1 = __builtin_amdgcn_mfma_f32_32x32x16_f16(kf1, qf, zero16(), 0, 0, 0);

        float pmax = e0[0];
        #pragma unroll
        for (int j = 1; j < 16; ++j) pmax = fmaxf(pmax, e0[j]);
        #pragma unroll
        for (int j = 0; j < 16; ++j) pmax = fmaxf(pmax, e1[j]);
        pmax = fmaxf(pmax, __shfl_xor(pmax, 32));
        const float m_new = fmaxf(m_i, pmax);
        const float sc = __expf(m_i - m_new);
        float psum = 0.0f;
        #pragma unroll
        for (int j = 0; j < 16; ++j) { e0[j] = __expf(e0[j] - m_new); psum += e0[j]; }
        #pragma unroll
        for (int j = 0; j < 16; ++j) { e1[j] = __expf(e1[j] - m_new); psum += e1[j]; }
        psum += __shfl_xor(psum, 32);
        l_i = l_i * sc + psum;
        m_i = m_new;

        if (chh == 0 && lane < 32) scs[qrow] = sc;   // per-ROW rescale factor

        // ---- P -> LDS (f16 pairs at E-layout key positions, XOR-swizzled) ----
        #pragma unroll
        for (int j = 0; j < 16; j += 2) {
            const int k0 = (j & 3) + 8 * (j >> 2) + 4 * hi;
            *(u32*)(pbase + ((2 * k0) ^ sw))      = pk2(e0[j], e0[j + 1]);
            *(u32*)(pbase + ((2 * k0 + 64) ^ sw)) = pk2(e1[j], e1[j + 1]);
        }

        __syncthreads();   // (2) Ps + scs visible to all waves

        // ---- THE FIX: rescale acc per D-layout ROW, not per lane ----
        #pragma unroll
        for (int r = 0; r < 16; ++r) {
            const float s = scs[qh * 32 + (r & 3) + 8 * (r >> 2) + 4 * hi];
            acc0[r] *= s;
            acc1[r] *= s;
        }

        // ---- PV: A-frag = P rows from LDS; B-frag = V cols from Vs ----
        const char* vbase = (const char*)(&Vs[bufp][0]);
        const int c0 = chh * 64 + lo;
        const int c1 = c0 + 32;
        #pragma unroll
        for (int ks = 0; ks < 4; ++ks) {
            const int koff = ks * 32 + hi * 16;
            const f16x8 pf = *(const f16x8*)(pbase + (koff ^ sw));
            const f16x8 v0 = *(const f16x8*)(vbase + c0 * 128 + (koff ^ ((c0 & 7) << 4)));
            const f16x8 v1 = *(const f16x8*)(vbase + c1 * 128 + (koff ^ ((c1 & 7) << 4)));
            acc0 = __builtin_amdgcn_mfma_f32_32x32x16_f16(pf, v0, acc0, 0, 0, 0);
            acc1 = __builtin_amdgcn_mfma_f32_32x32x16_f16(pf, v1, acc1, 0, 0, 0);
        }
    }

    if (chh == 0 && lane < 32) ls[qrow] = l_i;
    __syncthreads();

    #pragma unroll
    for (int r = 0; r < 16; ++r) {
        const int qloc = (r & 3) + 8 * (r >> 2) + 4 * hi;
        const float linv = 1.0f / ls[qh * 32 + qloc];
        const int q = n0 + qh * 32 + qloc;
        const size_t base = ((size_t)(b * NPIX + q)) << 7;  // *128
        const int cc0 = chh * 64 + lo;
        out[base + cc0]      = g * (acc0[r] * linv) + x[base + cc0];
        out[base + cc0 + 32] = g * (acc1[r] * linv) + x[base + cc0 + 32];
    }
}

extern "C" void kernel_launch(void* const* d_in, const int* in_sizes, int n_in,
                              void* d_out, int out_size, void* d_ws, size_t ws_size,
                              hipStream_t stream) {
    const float* x     = (const float*)d_in[0];
    const float* Wq    = (const float*)d_in[1];
    const float* bq    = (const float*)d_in[2];
    const float* Wk    = (const float*)d_in[3];
    const float* bk    = (const float*)d_in[4];
    const float* Wv    = (const float*)d_in[5];
    const float* bv    = (const float*)d_in[6];
    const float* gamma = (const float*)d_in[7];
    float* out = (float*)d_out;

    f16* Qg = (f16*)d_ws;                                   // 512 KB
    f16* Kg = Qg + (size_t)BATCH * NPIX * DQKD;             // 512 KB
    f16* Vg = Kg + (size_t)BATCH * NPIX * DQKD;             // 4 MB

    proj_mfma<<<dim3(BATCH * (NPIX / 64)), NTHREADS, 0, stream>>>(
        x, Wq, bq, Wk, bk, Wv, bv, Qg, Kg, Vg);
    attn_mfma<<<dim3(BATCH * (NPIX / QB)), NTHREADS, 0, stream>>>(
        Qg, Kg, Vg, x, gamma, out);
}

// Round 10
// 255.545 us; speedup vs baseline: 33.5459x; 1.1250x over previous
//
#include <hip/hip_runtime.h>
#include <math.h>
#include <stdint.h>

#define BATCH 4
#define CH 128
#define NPIX 4096
#define DQKD 16
#define QB 64
#define KVB 64

typedef _Float16 f16;
typedef _Float16 f16x8 __attribute__((ext_vector_type(8)));
typedef float f32x16 __attribute__((ext_vector_type(16)));
typedef uint32_t u32;

__device__ inline f32x16 zero16() {
    f32x16 z;
    #pragma unroll
    for (int i = 0; i < 16; ++i) z[i] = 0.0f;
    return z;
}

__device__ inline u32 pk2(float a, float b) {
    auto h = __builtin_amdgcn_cvt_pkrtz(a, b);   // 2 x f16 packed, RTZ
    return __builtin_bit_cast(u32, h);
}

// ---------------------------------------------------------------------------
// Projection (round-7-verified, empirically ~7-15us: 10240 blocks = 40/CU,
// fully coalesced x reads, L2/L3-resident re-reads). One thread = one (row,n).
// Outputs: Qg[b][n][16] f16, Kg[b][n][16] f16, Vg[b][c][n] f16.
// ---------------------------------------------------------------------------
__global__ __launch_bounds__(256) void proj_simple(
    const float* __restrict__ x,
    const float* __restrict__ Wq, const float* __restrict__ bq,
    const float* __restrict__ Wk, const float* __restrict__ bk,
    const float* __restrict__ Wv, const float* __restrict__ bv,
    f16* __restrict__ Qg, f16* __restrict__ Kg, f16* __restrict__ Vg)
{
    const int bid = blockIdx.x;                 // = ((b*160)+row)*16 + nc
    const int nc  = bid & 15;
    const int row = (bid >> 4) % 160;
    const int b   = bid / 2560;
    const int n   = nc * 256 + threadIdx.x;

    const float* wrow;
    float acc;
    if (row < 16)      { wrow = Wq + row * CH;        acc = bq[row]; }
    else if (row < 32) { wrow = Wk + (row - 16) * CH; acc = bk[row - 16]; }
    else               { wrow = Wv + (row - 32) * CH; acc = bv[row - 32]; }

    const float* xb = x + (size_t)b * CH * NPIX + n;  // x[b][c][n], c-stride NPIX
    #pragma unroll 4
    for (int c = 0; c < CH; ++c) acc += wrow[c] * xb[(size_t)c * NPIX];

    const f16 h = (f16)acc;
    if (row < 16)      Qg[(((size_t)(b * NPIX + n)) << 4) + row] = h;
    else if (row < 32) Kg[(((size_t)(b * NPIX + n)) << 4) + (row - 16)] = h;
    else               Vg[((size_t)(b * CH) + (row - 32)) * NPIX + n] = h;
}

// ---------------------------------------------------------------------------
// Flash attention (MFMA) + residual, in-block split-KV x2 for occupancy.
// 512 threads = 2 groups x 4 waves. Group g handles KV tiles [g*32, g*32+32),
// with private single-buffered Vs(16K)+Ps(8K) in a shared arena. Inner
// machinery (QK^T frags, softmax, P-write, Vs swizzle, per-D-row rescale) is
// the round-8 hardware-verified code. Flash-merge of the 2 partials in LDS.
// ---------------------------------------------------------------------------
__global__ __launch_bounds__(512, 4) void attn_mfma(
    const f16* __restrict__ Qg, const f16* __restrict__ Kg, const f16* __restrict__ Vg,
    const float* __restrict__ x, const float* __restrict__ gamma_p,
    float* __restrict__ out)
{
    __shared__ __align__(16) char arena[49152];    // [g]{Vs 16K, Ps 8K}; merge overlay 32K
    __shared__ float scs[2][64];
    __shared__ float ls[2][64];
    __shared__ float ms[2][64];

    int bid = blockIdx.x;
    bid = (bid & 7) * 32 + (bid >> 3);             // XCD swizzle (bijective, 256=8*32)
    const int b  = bid >> 6;
    const int n0 = (bid & 63) * 64;
    const int tid  = threadIdx.x;
    const int g    = tid >> 8;                     // KV-split group 0/1
    const int gtid = tid & 255;
    const int lane = tid & 63;
    const int w4   = gtid >> 6;                    // wave within group 0..3
    const int qh = w4 & 1, chh = w4 >> 1;
    const int lo = lane & 31, hi = lane >> 5;
    const float gm = gamma_p[0];

    char* VsG = arena + g * 24576;
    char* PsG = VsG + 16384;

    const f16* Vb = Vg + (size_t)b * CH * NPIX;
    const f16* Kb = Kg + ((size_t)(b * NPIX) << 4);

    const f16x8 qf = *(const f16x8*)(Qg + ((size_t)(b * NPIX + n0 + qh * 32 + lo) << 4) + hi * 8);

    const int qrow = qh * 32 + lo;                 // this lane's softmax row (E-layout)
    char* pbase = PsG + qrow * 128;
    const int sw = (lo & 7) << 4;

    uint4 sreg[4];
    auto load_tile = [&](int t) {                  // global -> regs
        const f16* vt = Vb + t * KVB;
        #pragma unroll
        for (int ps = 0; ps < 4; ++ps) {
            const int idx = ps * 256 + gtid;
            const int c = idx >> 3, ck = idx & 7;
            sreg[ps] = *(const uint4*)(vt + (size_t)c * NPIX + ck * 8);
        }
    };
    auto write_tile = [&]() {                      // regs -> swizzled Vs
        #pragma unroll
        for (int ps = 0; ps < 4; ++ps) {
            const int idx = ps * 256 + gtid;
            const int c = idx >> 3, ck = idx & 7;
            const int off = c * 128 + ((ck * 16) ^ ((c & 7) << 4));
            *(uint4*)(VsG + off) = sreg[ps];
        }
    };

    f32x16 acc0 = zero16(), acc1 = zero16();
    float m_i = -1e30f, l_i = 0.0f;

    const int T0 = g * 32;
    load_tile(T0);
    for (int t = 0; t < 32; ++t) {
        __syncthreads();   // (A) prev PV reads of Vs/Ps done -> safe to overwrite
        write_tile();

        // ---- QK^T (hardware-verified) ----
        const f16* kt = Kb + ((size_t)((T0 + t) * KVB) << 4);
        const f16x8 kf0 = *(const f16x8*)(kt + (lo << 4) + hi * 8);
        const f16x8 kf1 = *(const f16x8*)(kt + ((32 + lo) << 4) + hi * 8);

        f32x16 e0 = __builtin_amdgcn_mfma_f32_32x32x16_f16(kf0, qf, zero16(), 0, 0, 0);
        f32x16 e1 = __builtin_amdgcn_mfma_f32_32x32x16_f16(kf1, qf, zero16(), 0, 0, 0);

        float pmax = e0[0];
        #pragma unroll
        for (int j = 1; j < 16; ++j) pmax = fmaxf(pmax, e0[j]);
        #pragma unroll
        for (int j = 0; j < 16; ++j) pmax = fmaxf(pmax, e1[j]);
        pmax = fmaxf(pmax, __shfl_xor(pmax, 32));
        const float m_new = fmaxf(m_i, pmax);
        const float sc = __expf(m_i - m_new);
        float psum = 0.0f;
        #pragma unroll
        for (int j = 0; j < 16; ++j) { e0[j] = __expf(e0[j] - m_new); psum += e0[j]; }
        #pragma unroll
        for (int j = 0; j < 16; ++j) { e1[j] = __expf(e1[j] - m_new); psum += e1[j]; }
        psum += __shfl_xor(psum, 32);
        l_i = l_i * sc + psum;
        m_i = m_new;

        if (chh == 0 && lane < 32) scs[g][qrow] = sc;   // per-ROW rescale factor

        // ---- P -> LDS (E-layout key positions, XOR-swizzled) ----
        #pragma unroll
        for (int j = 0; j < 16; j += 2) {
            const int k0 = (j & 3) + 8 * (j >> 2) + 4 * hi;
            *(u32*)(pbase + ((2 * k0) ^ sw))      = pk2(e0[j], e0[j + 1]);
            *(u32*)(pbase + ((2 * k0 + 64) ^ sw)) = pk2(e1[j], e1[j + 1]);
        }

        if (t < 31) load_tile(T0 + t + 1);   // issue next-tile loads (hide under PV)

        __syncthreads();   // (B) Vs + Ps + scs ready

        // ---- rescale acc per D-layout ROW (round-8 fix) ----
        #pragma unroll
        for (int r = 0; r < 16; ++r) {
            const float s = scs[g][qh * 32 + (r & 3) + 8 * (r >> 2) + 4 * hi];
            acc0[r] *= s;
            acc1[r] *= s;
        }

        // ---- PV: A-frag = P rows from Ps; B-frag = V cols from Vs ----
        const int c0 = chh * 64 + lo;
        const int c1 = c0 + 32;
        #pragma unroll
        for (int ks = 0; ks < 4; ++ks) {
            const int koff = ks * 32 + hi * 16;
            const f16x8 pf = *(const f16x8*)(pbase + (koff ^ sw));
            const f16x8 v0 = *(const f16x8*)(VsG + c0 * 128 + (koff ^ ((c0 & 7) << 4)));
            const f16x8 v1 = *(const f16x8*)(VsG + c1 * 128 + (koff ^ ((c1 & 7) << 4)));
            acc0 = __builtin_amdgcn_mfma_f32_32x32x16_f16(pf, v0, acc0, 0, 0, 0);
            acc1 = __builtin_amdgcn_mfma_f32_32x32x16_f16(pf, v1, acc1, 0, 0, 0);
        }
    }

    // ---- flash-merge of the two KV-half partials ----
    if (chh == 0 && lane < 32) { ms[g][qrow] = m_i; ls[g][qrow] = l_i; }
    __syncthreads();   // partial m,l published; Vs/Ps dead

    float* macc = (float*)arena;   // overlay [64 q][128 c] f32 = 32 KB
    if (g == 0) {
        #pragma unroll
        for (int r = 0; r < 16; ++r) {
            const int qloc = (r & 3) + 8 * (r >> 2) + 4 * hi;
            const int q = qh * 32 + qloc;
            const float f0 = __expf(ms[0][q] - fmaxf(ms[0][q], ms[1][q]));
            const int c0 = chh * 64 + lo;
            macc[q * 128 + c0]      = acc0[r] * f0;
            macc[q * 128 + c0 + 32] = acc1[r] * f0;
        }
    }
    __syncthreads();
    if (g == 1) {
        #pragma unroll
        for (int r = 0; r < 16; ++r) {
            const int qloc = (r & 3) + 8 * (r >> 2) + 4 * hi;
            const int q = qh * 32 + qloc;
            const float m0 = ms[0][q], m1 = ms[1][q];
            const float mstar = fmaxf(m0, m1);
            const float f0 = __expf(m0 - mstar), f1 = __expf(m1 - mstar);
            const float inv = 1.0f / (ls[0][q] * f0 + ls[1][q] * f1);
            const size_t base = ((size_t)(b * NPIX + n0 + q)) << 7;  // *128
            const int c0 = chh * 64 + lo;
            const float o0 = (macc[q * 128 + c0]      + acc0[r] * f1) * inv;
            const float o1 = (macc[q * 128 + c0 + 32] + acc1[r] * f1) * inv;
            out[base + c0]      = gm * o0 + x[base + c0];
            out[base + c0 + 32] = gm * o1 + x[base + c0 + 32];
        }
    }
}

extern "C" void kernel_launch(void* const* d_in, const int* in_sizes, int n_in,
                              void* d_out, int out_size, void* d_ws, size_t ws_size,
                              hipStream_t stream) {
    const float* x     = (const float*)d_in[0];
    const float* Wq    = (const float*)d_in[1];
    const float* bq    = (const float*)d_in[2];
    const float* Wk    = (const float*)d_in[3];
    const float* bk    = (const float*)d_in[4];
    const float* Wv    = (const float*)d_in[5];
    const float* bv    = (const float*)d_in[6];
    const float* gamma = (const float*)d_in[7];
    float* out = (float*)d_out;

    f16* Qg = (f16*)d_ws;                                   // 512 KB
    f16* Kg = Qg + (size_t)BATCH * NPIX * DQKD;             // 512 KB
    f16* Vg = Kg + (size_t)BATCH * NPIX * DQKD;             // 4 MB

    proj_simple<<<dim3(BATCH * 160 * 16), 256, 0, stream>>>(
        x, Wq, bq, Wk, bk, Wv, bv, Qg, Kg, Vg);
    attn_mfma<<<dim3(BATCH * (NPIX / QB)), 512, 0, stream>>>(
        Qg, Kg, Vg, x, gamma, out);
}